// Round 10
// baseline (463.376 us; speedup 1.0000x reference)
//
#include <hip/hip_runtime.h>
#include <hip/hip_bf16.h>

typedef _Float16 f16x8 __attribute__((ext_vector_type(8)));
typedef _Float16 f16x4 __attribute__((ext_vector_type(4)));
typedef float    f32x4 __attribute__((ext_vector_type(4)));

#define LOG2E  1.44269504f
#define LOG2E2 2.88539008f

// Gates arrive PRE-SCALED (scale folded into weights/bias):
//   i~ = -log2e*i, f~ = -log2e*f, g~ = 2log2e*g, o~ = -log2e*o
// c' = (c*B*C + A*(eg-1)) * rcp(A*B*C);  h = (ec-1)*rcp((1+eo)*(1+ec))
__device__ __forceinline__ float cellT(float fi, float ff, float fg, float fo, float& c) {
    float ei = __builtin_amdgcn_exp2f(fi);
    float ef = __builtin_amdgcn_exp2f(ff);
    float eg = __builtin_amdgcn_exp2f(fg);
    float A  = 1.0f + ef;
    float B  = 1.0f + ei;
    float C  = 1.0f + eg;
    float Cm2 = eg - 1.0f;
    float BC = B * C;
    float cn = fmaf(c, BC, A * Cm2) * __builtin_amdgcn_rcpf(A * BC);
    c = cn;
    float eo = __builtin_amdgcn_exp2f(fo);
    float ec = __builtin_amdgcn_exp2f(LOG2E2 * cn);
    return (ec - 1.0f) * __builtin_amdgcn_rcpf((1.0f + eo) * (1.0f + ec));
}

__device__ __forceinline__ f16x8 afrag8(const float* __restrict__ p, float s) {
    const float4 w0 = *(const float4*)p;
    const float4 w1 = *(const float4*)(p + 4);
    f16x8 v;
    v[0] = (_Float16)(w0.x * s); v[1] = (_Float16)(w0.y * s);
    v[2] = (_Float16)(w0.z * s); v[3] = (_Float16)(w0.w * s);
    v[4] = (_Float16)(w1.x * s); v[5] = (_Float16)(w1.y * s);
    v[6] = (_Float16)(w1.z * s); v[7] = (_Float16)(w1.w * s);
    return v;
}

__device__ __forceinline__ float gscale(int nb) {
    return ((nb >> 1) == 2) ? LOG2E2 : -LOG2E;
}

// j-permutation (R9-verified): block nb, A/C row m -> weight column j. Lane
// (quad,n0)'s 8 cell outputs land exactly in next step's B-frag k-slice.
__device__ __forceinline__ int jperm(int nb, int m) {
    return 8 * (m >> 2) + 4 * (nb & 1) + (m & 3);
}

#define HAVE_K16 __has_builtin(__builtin_amdgcn_mfma_f32_16x16x16f16)

// ---------------------------------------------------------------------------
// Fully fused: one wave = (model, 16 samples). Phase A: L0-bwd scan -> 15
// B-frags into wave-private LDS (15 KB). Phase B: L0-fwd + L1-fwd fused scan
// consuming LDS hist. Phase C: 1-step L1-bwd. Phase D: FC + mask + atomics.
// No inter-wave communication at all (no __syncthreads, no global scratch).
// grid = (1024, 2[model]); block = 256 (4 waves).
// ---------------------------------------------------------------------------
__global__ __launch_bounds__(256, 1) void lstm_all(
    const float* __restrict__ dir_input,      // [32768,6]
    const float* __restrict__ pos,            // [32768,30,4]
    const float* __restrict__ lvl_Wih0, const float* __restrict__ lvl_Whh0,
    const float* __restrict__ lvl_b0,
    const float* __restrict__ lvl_Wih1, const float* __restrict__ lvl_Whh1,
    const float* __restrict__ lvl_b1,
    const float* __restrict__ vor_Wih0, const float* __restrict__ vor_Whh0,
    const float* __restrict__ vor_b0,
    const float* __restrict__ vor_Wih1, const float* __restrict__ vor_Whh1,
    const float* __restrict__ vor_b1,
    const float* __restrict__ lvl_fc_W, const float* __restrict__ lvl_fc_b,
    const float* __restrict__ vor_fc_W, const float* __restrict__ vor_fc_b,
    float* __restrict__ out)                  // [32768,2], pre-zeroed
{
    const int lane = threadIdx.x & 63;
    const int wv   = threadIdx.x >> 6;
    const int n0   = lane & 15;
    const int quad = lane >> 4;
    const int tile = blockIdx.x * 4 + wv;      // 0..4095
    const int m    = blockIdx.y;

    const float* Wih0 = m ? vor_Wih0 : lvl_Wih0;   // [2][128][4]
    const float* Whh0 = m ? vor_Whh0 : lvl_Whh0;   // [2][128][32]
    const float* B0   = m ? vor_b0   : lvl_b0;     // [2][128]
    const float* Wih1 = m ? vor_Wih1 : lvl_Wih1;   // [2][128][64]
    const float* Whh1 = m ? vor_Whh1 : lvl_Whh1;   // [2][128][32]
    const float* B1   = m ? vor_b1   : lvl_b1;     // [2][128]

    // wave-private hist: 15 t x 512 f16 (B-frag layout, lane*8)
    __shared__ _Float16 hist_s[4][15 * 512];
    _Float16* H = hist_s[wv] + lane * 8;

    const int s0    = tile * 16 + n0;
    const int b     = s0 & 32767;
    const int hf    = s0 >> 15;
    const float* xbase = pos + ((size_t)b * 30 + hf * 15) * 4;

    const f32x4 z4 = {0.0f, 0.0f, 0.0f, 0.0f};
    f16x8 hb14;                                // L0-bwd h at t=14 (phase C input)

    // ================= Phase A: L0 backward scan (t = 14..0) =================
    {
        const float* Wih = Wih0 + 128 * 4;     // dir 1
        const float* Whh = Whh0 + 128 * 32;
        const float* bs  = B0 + 128;

        f16x8 WhhA[8];
#if HAVE_K16
        f16x4 WihA[8];
#else
        f16x8 WihA[8];
#endif
#pragma unroll
        for (int nb = 0; nb < 8; ++nb) {
            const int J = (nb >> 1) * 32 + jperm(nb, n0);
            const float s = gscale(nb);
            WhhA[nb] = afrag8(Whh + J * 32 + quad * 8, s);
#if HAVE_K16
            f16x4 v = {(_Float16)0.0f, (_Float16)0.0f, (_Float16)0.0f, (_Float16)0.0f};
            if (quad == 0) {
                const float4 w = *(const float4*)(Wih + J * 4);
                v[0] = (_Float16)(w.x * s); v[1] = (_Float16)(w.y * s);
                v[2] = (_Float16)(w.z * s); v[3] = (_Float16)(w.w * s);
            } else if (quad == 1) {
                v[0] = (_Float16)(bs[J] * s);
            }
            WihA[nb] = v;
#else
            f16x8 v;
#pragma unroll
            for (int r = 0; r < 8; ++r) v[r] = (_Float16)0.0f;
            if (quad == 0) {
                const float4 w = *(const float4*)(Wih + J * 4);
                v[0] = (_Float16)(w.x * s); v[1] = (_Float16)(w.y * s);
                v[2] = (_Float16)(w.z * s); v[3] = (_Float16)(w.w * s);
                v[4] = (_Float16)(bs[J] * s);
            }
            WihA[nb] = v;
#endif
        }

        float c[4][2];
#pragma unroll
        for (int r = 0; r < 4; ++r) { c[r][0] = 0.0f; c[r][1] = 0.0f; }
        f16x8 hB;
#pragma unroll
        for (int r = 0; r < 8; ++r) hB[r] = (_Float16)0.0f;

        const float* xp = xbase + 14 * 4;

#pragma unroll 1
        for (int ti = 0; ti < 15; ++ti) {
            const int t = 14 - ti;
            const float4 xv = *(const float4*)xp;
            xp -= 4;
#if HAVE_K16
            f16x4 xB = {(_Float16)0.0f, (_Float16)0.0f, (_Float16)0.0f, (_Float16)0.0f};
            if (quad == 0) {
                xB[0] = (_Float16)xv.x; xB[1] = (_Float16)xv.y;
                xB[2] = (_Float16)xv.z; xB[3] = (_Float16)xv.w;
            } else if (quad == 1) {
                xB[0] = (_Float16)1.0f;
            }
#else
            f16x8 xB;
#pragma unroll
            for (int r = 0; r < 8; ++r) xB[r] = (_Float16)0.0f;
            if (quad == 0) {
                xB[0] = (_Float16)xv.x; xB[1] = (_Float16)xv.y;
                xB[2] = (_Float16)xv.z; xB[3] = (_Float16)xv.w;
                xB[4] = (_Float16)1.0f;
            }
#endif
            f32x4 acc[8];
#pragma unroll
            for (int nb = 0; nb < 8; ++nb)
#if HAVE_K16
                acc[nb] = __builtin_amdgcn_mfma_f32_16x16x16f16(WihA[nb], xB, z4, 0, 0, 0);
#else
                acc[nb] = __builtin_amdgcn_mfma_f32_16x16x32_f16(WihA[nb], xB, z4, 0, 0, 0);
#endif
#pragma unroll
            for (int nb = 0; nb < 8; ++nb)
                acc[nb] = __builtin_amdgcn_mfma_f32_16x16x32_f16(WhhA[nb], hB, acc[nb], 0, 0, 0);

            f16x8 nh;
#pragma unroll
            for (int r = 0; r < 4; ++r) {
                nh[r]     = (_Float16)cellT(acc[0][r], acc[2][r], acc[4][r], acc[6][r], c[r][0]);
                nh[4 + r] = (_Float16)cellT(acc[1][r], acc[3][r], acc[5][r], acc[7][r], c[r][1]);
            }
            hB = nh;
            *(f16x8*)(H + t * 512) = hB;       // wave-private, no barrier needed
        }
    }

    // ============ Phase B: L0 forward + L1 forward fused (t = 0..14) ============
    f16x8 WhhF[8];
#if HAVE_K16
    f16x4 WihF[8];
#else
    f16x8 WihF[8];
#endif
    f16x8 WA[8], WB[8], WH[8];
    f32x4 biasv[8];
#pragma unroll
    for (int nb = 0; nb < 8; ++nb) {
        const int g = nb >> 1, p = nb & 1;
        const int J = g * 32 + jperm(nb, n0);
        const float s = gscale(nb);
        WhhF[nb] = afrag8(Whh0 + J * 32 + quad * 8, s);
#if HAVE_K16
        {
            f16x4 v = {(_Float16)0.0f, (_Float16)0.0f, (_Float16)0.0f, (_Float16)0.0f};
            if (quad == 0) {
                const float4 w = *(const float4*)(Wih0 + J * 4);
                v[0] = (_Float16)(w.x * s); v[1] = (_Float16)(w.y * s);
                v[2] = (_Float16)(w.z * s); v[3] = (_Float16)(w.w * s);
            } else if (quad == 1) {
                v[0] = (_Float16)(B0[J] * s);
            }
            WihF[nb] = v;
        }
#else
        {
            f16x8 v;
#pragma unroll
            for (int r = 0; r < 8; ++r) v[r] = (_Float16)0.0f;
            if (quad == 0) {
                const float4 w = *(const float4*)(Wih0 + J * 4);
                v[0] = (_Float16)(w.x * s); v[1] = (_Float16)(w.y * s);
                v[2] = (_Float16)(w.z * s); v[3] = (_Float16)(w.w * s);
                v[4] = (_Float16)(B0[J] * s);
            }
            WihF[nb] = v;
        }
#endif
        WA[nb] = afrag8(Wih1 + J * 64 + quad * 8, s);
        WB[nb] = afrag8(Wih1 + J * 64 + 32 + quad * 8, s);
        WH[nb] = afrag8(Whh1 + J * 32 + quad * 8, s);
        const float4 bq = *(const float4*)(B1 + g * 32 + 8 * quad + 4 * p);
        f32x4 bv; bv[0] = bq.x * s; bv[1] = bq.y * s; bv[2] = bq.z * s; bv[3] = bq.w * s;
        biasv[nb] = bv;
    }

    float c0[4][2], c1[4][2];
#pragma unroll
    for (int r = 0; r < 4; ++r) {
        c0[r][0] = 0.0f; c0[r][1] = 0.0f;
        c1[r][0] = 0.0f; c1[r][1] = 0.0f;
    }
    f16x8 h0B, h1B, hb_t;
#pragma unroll
    for (int r = 0; r < 8; ++r) { h0B[r] = (_Float16)0.0f; h1B[r] = (_Float16)0.0f; }
    float h1f_a[4], h1f_b[4];

    const float* xp = xbase;

#pragma unroll 1
    for (int t = 0; t < 15; ++t) {
        hb_t = *(const f16x8*)(H + t * 512);   // this step's L0-bwd hidden
        const float4 xv = *(const float4*)xp;
        xp += 4;
#if HAVE_K16
        f16x4 xB = {(_Float16)0.0f, (_Float16)0.0f, (_Float16)0.0f, (_Float16)0.0f};
        if (quad == 0) {
            xB[0] = (_Float16)xv.x; xB[1] = (_Float16)xv.y;
            xB[2] = (_Float16)xv.z; xB[3] = (_Float16)xv.w;
        } else if (quad == 1) {
            xB[0] = (_Float16)1.0f;
        }
#else
        f16x8 xB;
#pragma unroll
        for (int r = 0; r < 8; ++r) xB[r] = (_Float16)0.0f;
        if (quad == 0) {
            xB[0] = (_Float16)xv.x; xB[1] = (_Float16)xv.y;
            xB[2] = (_Float16)xv.z; xB[3] = (_Float16)xv.w;
            xB[4] = (_Float16)1.0f;
        }
#endif
        // L0 forward step
        f32x4 acc[8];
#pragma unroll
        for (int nb = 0; nb < 8; ++nb)
#if HAVE_K16
            acc[nb] = __builtin_amdgcn_mfma_f32_16x16x16f16(WihF[nb], xB, z4, 0, 0, 0);
#else
            acc[nb] = __builtin_amdgcn_mfma_f32_16x16x32_f16(WihF[nb], xB, z4, 0, 0, 0);
#endif
#pragma unroll
        for (int nb = 0; nb < 8; ++nb)
            acc[nb] = __builtin_amdgcn_mfma_f32_16x16x32_f16(WhhF[nb], h0B, acc[nb], 0, 0, 0);
        {
            f16x8 nh;
#pragma unroll
            for (int r = 0; r < 4; ++r) {
                nh[r]     = (_Float16)cellT(acc[0][r], acc[2][r], acc[4][r], acc[6][r], c0[r][0]);
                nh[4 + r] = (_Float16)cellT(acc[1][r], acc[3][r], acc[5][r], acc[7][r], c0[r][1]);
            }
            h0B = nh;
        }

        // L1 forward step
#pragma unroll
        for (int nb = 0; nb < 8; ++nb)
            acc[nb] = __builtin_amdgcn_mfma_f32_16x16x32_f16(WA[nb], h0B, biasv[nb], 0, 0, 0);
#pragma unroll
        for (int nb = 0; nb < 8; ++nb)
            acc[nb] = __builtin_amdgcn_mfma_f32_16x16x32_f16(WB[nb], hb_t, acc[nb], 0, 0, 0);
#pragma unroll
        for (int nb = 0; nb < 8; ++nb)
            acc[nb] = __builtin_amdgcn_mfma_f32_16x16x32_f16(WH[nb], h1B, acc[nb], 0, 0, 0);
        {
            f16x8 nh;
#pragma unroll
            for (int r = 0; r < 4; ++r) {
                float ha  = cellT(acc[0][r], acc[2][r], acc[4][r], acc[6][r], c1[r][0]);
                float hbv = cellT(acc[1][r], acc[3][r], acc[5][r], acc[7][r], c1[r][1]);
                h1f_a[r] = ha; h1f_b[r] = hbv;
                nh[r] = (_Float16)ha; nh[4 + r] = (_Float16)hbv;
            }
            h1B = nh;
        }
    }
    hb14 = hb_t;                               // L0-bwd h at t=14
    const f16x8 a_f = h0B;                     // L0-fwd h at t=14

    // ============ Phase C: L1 backward, single step (f-gate dead) ============
    float h1b_a[4], h1b_b[4];
    {
        const float* Wb = Wih1 + 128 * 64;     // dir 1
        const float* bb = B1 + 128;
        const int nbs[6] = {0, 1, 4, 5, 6, 7}; // i, g, o slices
        f32x4 accb[6];
#pragma unroll
        for (int q6 = 0; q6 < 6; ++q6) {
            const int nb = nbs[q6];
            const int g = nb >> 1, p = nb & 1;
            const int J = g * 32 + jperm(nb, n0);
            const float s = gscale(nb);
            const f16x8 wa = afrag8(Wb + J * 64 + quad * 8, s);
            const f16x8 wb = afrag8(Wb + J * 64 + 32 + quad * 8, s);
            const float4 bq = *(const float4*)(bb + g * 32 + 8 * quad + 4 * p);
            f32x4 bv; bv[0] = bq.x * s; bv[1] = bq.y * s; bv[2] = bq.z * s; bv[3] = bq.w * s;
            f32x4 a = __builtin_amdgcn_mfma_f32_16x16x32_f16(wa, a_f, bv, 0, 0, 0);
            a = __builtin_amdgcn_mfma_f32_16x16x32_f16(wb, hb14, a, 0, 0, 0);
            accb[q6] = a;
        }
#pragma unroll
        for (int r = 0; r < 4; ++r) {
#pragma unroll
            for (int p = 0; p < 2; ++p) {
                const float i_ = accb[0 + p][r];
                const float g_ = accb[2 + p][r];
                const float o_ = accb[4 + p][r];
                float ei = __builtin_amdgcn_exp2f(i_);
                float eg = __builtin_amdgcn_exp2f(g_);
                float Bv = 1.0f + ei;
                float C  = 1.0f + eg;
                float cv = (eg - 1.0f) * __builtin_amdgcn_rcpf(Bv * C);
                float eo = __builtin_amdgcn_exp2f(o_);
                float ec = __builtin_amdgcn_exp2f(LOG2E2 * cv);
                float h = (ec - 1.0f) * __builtin_amdgcn_rcpf((1.0f + eo) * (1.0f + ec));
                if (p == 0) h1b_a[r] = h; else h1b_b[r] = h;
            }
        }
    }

    // ============ Phase D: FC + masks + atomic combine ============
    const int sbase = tile * 16;
    const int halfU = sbase >> 15;             // wave-uniform

    float pr[2];
#pragma unroll
    for (int o = 0; o < 2; ++o) {
        const float* Wr = (m == 0) ? (lvl_fc_W + o * 64)
                                   : (vor_fc_W + o * 128 + halfU * 64);
        const float4 wfa = *(const float4*)(Wr + 8 * quad);
        const float4 wfb = *(const float4*)(Wr + 8 * quad + 4);
        const float4 wba = *(const float4*)(Wr + 32 + 8 * quad);
        const float4 wbb = *(const float4*)(Wr + 32 + 8 * quad + 4);
        float a = wfa.x * h1f_a[0] + wfa.y * h1f_a[1]
                + wfa.z * h1f_a[2] + wfa.w * h1f_a[3];
        a += wfb.x * h1f_b[0] + wfb.y * h1f_b[1]
           + wfb.z * h1f_b[2] + wfb.w * h1f_b[3];
        a += wba.x * h1b_a[0] + wba.y * h1b_a[1]
           + wba.z * h1b_a[2] + wba.w * h1b_a[3];
        a += wbb.x * h1b_b[0] + wbb.y * h1b_b[1]
           + wbb.z * h1b_b[2] + wbb.w * h1b_b[3];
        pr[o] = a;
    }
#pragma unroll
    for (int o = 0; o < 2; ++o) {
        pr[o] += __shfl_xor(pr[o], 16);
        pr[o] += __shfl_xor(pr[o], 32);
    }

    if (quad == 0) {
        const float* dp = dir_input + (size_t)b * 6;
        float mx = dp[0];
        int dmax = 0;
#pragma unroll
        for (int i = 1; i < 6; ++i) {
            const float v = dp[i];
            if (v > mx) { mx = v; dmax = i; }
        }
        float mask, b0v, b1v;
        if (m == 0) {
            mask = (halfU == 0) ? ((dmax == 2 || dmax == 3) ? 1.0f : 0.0f)
                                : ((dmax == 0 || dmax == 5) ? 1.0f : 0.0f);
            b0v = lvl_fc_b[0]; b1v = lvl_fc_b[1];
        } else {
            mask = (dmax == 1 || dmax == 4) ? 1.0f : 0.0f;
            b0v = (halfU == 0) ? vor_fc_b[0] : 0.0f;
            b1v = (halfU == 0) ? vor_fc_b[1] : 0.0f;
        }
        atomicAdd(out + (size_t)b * 2 + 0, (pr[0] + b0v) * mask);
        atomicAdd(out + (size_t)b * 2 + 1, (pr[1] + b1v) * mask);
    }
}

extern "C" void kernel_launch(void* const* d_in, const int* in_sizes, int n_in,
                              void* d_out, int out_size, void* d_ws, size_t ws_size,
                              hipStream_t stream) {
    const float* dir_input = (const float*)d_in[0];
    const float* pos       = (const float*)d_in[1];
    const float* lvl_Wih0  = (const float*)d_in[2];
    const float* lvl_Whh0  = (const float*)d_in[3];
    const float* lvl_b0    = (const float*)d_in[4];
    const float* lvl_Wih1  = (const float*)d_in[5];
    const float* lvl_Whh1  = (const float*)d_in[6];
    const float* lvl_b1    = (const float*)d_in[7];
    const float* vor_Wih0  = (const float*)d_in[8];
    const float* vor_Whh0  = (const float*)d_in[9];
    const float* vor_b0    = (const float*)d_in[10];
    const float* vor_Wih1  = (const float*)d_in[11];
    const float* vor_Whh1  = (const float*)d_in[12];
    const float* vor_b1    = (const float*)d_in[13];
    const float* lvl_fc_W  = (const float*)d_in[14];
    const float* lvl_fc_b  = (const float*)d_in[15];
    const float* vor_fc_W  = (const float*)d_in[16];
    const float* vor_fc_b  = (const float*)d_in[17];
    float* out = (float*)d_out;

    (void)in_sizes; (void)n_in; (void)d_ws; (void)ws_size;

    hipMemsetAsync(d_out, 0, (size_t)out_size * sizeof(float), stream);

    dim3 grid(1024, 2, 1);   // 4096 tiles x 2 models, 4 waves/block
    dim3 blk(256, 1, 1);
    hipLaunchKernelGGL(lstm_all, grid, blk, 0, stream,
                       dir_input, pos,
                       lvl_Wih0, lvl_Whh0, lvl_b0, lvl_Wih1, lvl_Whh1, lvl_b1,
                       vor_Wih0, vor_Whh0, vor_b0, vor_Wih1, vor_Whh1, vor_b1,
                       lvl_fc_W, lvl_fc_b, vor_fc_W, vor_fc_b,
                       out);
}

// Round 13
// 350.507 us; speedup vs baseline: 1.3220x; 1.3220x over previous
//
#include <hip/hip_runtime.h>
#include <hip/hip_bf16.h>

typedef _Float16 f16x8 __attribute__((ext_vector_type(8)));
typedef _Float16 f16x4 __attribute__((ext_vector_type(4)));
typedef float    f32x4 __attribute__((ext_vector_type(4)));

#define LOG2E  1.44269504f
#define LOG2E2 2.88539008f

// Gates arrive PRE-SCALED (scale folded into weights/bias):
//   i~ = -log2e*i, f~ = -log2e*f, g~ = 2log2e*g, o~ = -log2e*o
// c' = (c*B*C + A*(eg-1)) * rcp(A*B*C);  h = (ec-1)*rcp((1+eo)*(1+ec))
__device__ __forceinline__ float cellT(float fi, float ff, float fg, float fo, float& c) {
    float ei = __builtin_amdgcn_exp2f(fi);
    float ef = __builtin_amdgcn_exp2f(ff);
    float eg = __builtin_amdgcn_exp2f(fg);
    float A  = 1.0f + ef;
    float B  = 1.0f + ei;
    float C  = 1.0f + eg;
    float Cm2 = eg - 1.0f;
    float BC = B * C;
    float cn = fmaf(c, BC, A * Cm2) * __builtin_amdgcn_rcpf(A * BC);
    c = cn;
    float eo = __builtin_amdgcn_exp2f(fo);
    float ec = __builtin_amdgcn_exp2f(LOG2E2 * cn);
    return (ec - 1.0f) * __builtin_amdgcn_rcpf((1.0f + eo) * (1.0f + ec));
}

__device__ __forceinline__ f16x8 afrag8(const float* __restrict__ p, float s) {
    const float4 w0 = *(const float4*)p;
    const float4 w1 = *(const float4*)(p + 4);
    f16x8 v;
    v[0] = (_Float16)(w0.x * s); v[1] = (_Float16)(w0.y * s);
    v[2] = (_Float16)(w0.z * s); v[3] = (_Float16)(w0.w * s);
    v[4] = (_Float16)(w1.x * s); v[5] = (_Float16)(w1.y * s);
    v[6] = (_Float16)(w1.z * s); v[7] = (_Float16)(w1.w * s);
    return v;
}

__device__ __forceinline__ float gscale(int nb) {
    return ((nb >> 1) == 2) ? LOG2E2 : -LOG2E;
}

// j-permutation (R9-verified): block nb, A/C row m -> weight column j.
// Lane (quad,n0)'s 8 cell outputs land exactly in next step's B-frag k-slice.
__device__ __forceinline__ int jperm(int nb, int m) {
    return 8 * (m >> 2) + 4 * (nb & 1) + (m & 3);
}

#define HAVE_K16 __has_builtin(__builtin_amdgcn_mfma_f32_16x16x16f16)

// ---------------------------------------------------------------------------
// K1 (R9-verified, unchanged): layer-0 scans, zero-LDS feedback.
// 1 wave = 16 samples. grid = (NT/4, 4[model*2+dir]).
// hist: hist[(m*NT+tile)*15*1024 + t*1024 + dir*512 + lane*8] (f16x8 B-frags).
// ---------------------------------------------------------------------------
__global__ __launch_bounds__(256, 4) void k1_l0(
    const float* __restrict__ pos,            // [32768,30,4]
    const float* __restrict__ lvl_Wih0, const float* __restrict__ lvl_Whh0,
    const float* __restrict__ lvl_b0,
    const float* __restrict__ vor_Wih0, const float* __restrict__ vor_Whh0,
    const float* __restrict__ vor_b0,
    _Float16* __restrict__ hist, int chunk_base, int NT)
{
    const int lane = threadIdx.x & 63;
    const int wv   = threadIdx.x >> 6;
    const int n0   = lane & 15;
    const int quad = lane >> 4;
    const int tile = blockIdx.x * 4 + wv;
    const int m    = blockIdx.y >> 1;
    const int dir  = blockIdx.y & 1;

    const float* Wih = (m ? vor_Wih0 : lvl_Wih0) + dir * 128 * 4;   // [128][4]
    const float* Whh = (m ? vor_Whh0 : lvl_Whh0) + dir * 128 * 32;  // [128][32]
    const float* bs  = (m ? vor_b0   : lvl_b0)   + dir * 128;       // [128]

    f16x8 WhhA[8];
#if HAVE_K16
    f16x4 WihA[8];
#else
    f16x8 WihA[8];
#endif
#pragma unroll
    for (int nb = 0; nb < 8; ++nb) {
        const int J = (nb >> 1) * 32 + jperm(nb, n0);   // A-frag row, permuted
        const float s = gscale(nb);
        WhhA[nb] = afrag8(Whh + J * 32 + quad * 8, s);
#if HAVE_K16
        f16x4 v = {(_Float16)0.0f, (_Float16)0.0f, (_Float16)0.0f, (_Float16)0.0f};
        if (quad == 0) {
            const float4 w = *(const float4*)(Wih + J * 4);
            v[0] = (_Float16)(w.x * s); v[1] = (_Float16)(w.y * s);
            v[2] = (_Float16)(w.z * s); v[3] = (_Float16)(w.w * s);
        } else if (quad == 1) {
            v[0] = (_Float16)(bs[J] * s);     // k=4 bias slot
        }
        WihA[nb] = v;
#else
        f16x8 v;
#pragma unroll
        for (int r = 0; r < 8; ++r) v[r] = (_Float16)0.0f;
        if (quad == 0) {
            const float4 w = *(const float4*)(Wih + J * 4);
            v[0] = (_Float16)(w.x * s); v[1] = (_Float16)(w.y * s);
            v[2] = (_Float16)(w.z * s); v[3] = (_Float16)(w.w * s);
            v[4] = (_Float16)(bs[J] * s);
        }
        WihA[nb] = v;
#endif
    }

    const int s0   = chunk_base + tile * 16 + n0;
    const int b    = s0 & 32767;
    const int hf   = s0 >> 15;
    const float* xp = pos + ((size_t)b * 30 + hf * 15 + (dir ? 14 : 0)) * 4;
    const int xstep = dir ? -4 : 4;

    _Float16* hp = hist + ((size_t)(m * NT + tile)) * 15 * 1024
                 + (size_t)(dir ? 14 : 0) * 1024 + dir * 512 + lane * 8;
    const int hstep = dir ? -1024 : 1024;

    float c[4][2];
#pragma unroll
    for (int r = 0; r < 4; ++r) { c[r][0] = 0.0f; c[r][1] = 0.0f; }

    f16x8 hB;
#pragma unroll
    for (int r = 0; r < 8; ++r) hB[r] = (_Float16)0.0f;

    const f32x4 z4 = {0.0f, 0.0f, 0.0f, 0.0f};

#pragma unroll 1
    for (int ti = 0; ti < 15; ++ti) {
        const float4 xv = *(const float4*)xp;
        xp += xstep;
#if HAVE_K16
        f16x4 xB = {(_Float16)0.0f, (_Float16)0.0f, (_Float16)0.0f, (_Float16)0.0f};
        if (quad == 0) {
            xB[0] = (_Float16)xv.x; xB[1] = (_Float16)xv.y;
            xB[2] = (_Float16)xv.z; xB[3] = (_Float16)xv.w;
        } else if (quad == 1) {
            xB[0] = (_Float16)1.0f;
        }
#else
        f16x8 xB;
#pragma unroll
        for (int r = 0; r < 8; ++r) xB[r] = (_Float16)0.0f;
        if (quad == 0) {
            xB[0] = (_Float16)xv.x; xB[1] = (_Float16)xv.y;
            xB[2] = (_Float16)xv.z; xB[3] = (_Float16)xv.w;
            xB[4] = (_Float16)1.0f;
        }
#endif

        f32x4 acc[8];
#pragma unroll
        for (int nb = 0; nb < 8; ++nb)
#if HAVE_K16
            acc[nb] = __builtin_amdgcn_mfma_f32_16x16x16f16(WihA[nb], xB, z4, 0, 0, 0);
#else
            acc[nb] = __builtin_amdgcn_mfma_f32_16x16x32_f16(WihA[nb], xB, z4, 0, 0, 0);
#endif
#pragma unroll
        for (int nb = 0; nb < 8; ++nb)
            acc[nb] = __builtin_amdgcn_mfma_f32_16x16x32_f16(WhhA[nb], hB, acc[nb], 0, 0, 0);

        // outputs pack DIRECTLY into next step's B-frag (jperm). No LDS.
        f16x8 nh;
#pragma unroll
        for (int r = 0; r < 4; ++r) {
            nh[r]     = (_Float16)cellT(acc[0][r], acc[2][r], acc[4][r], acc[6][r], c[r][0]);
            nh[4 + r] = (_Float16)cellT(acc[1][r], acc[3][r], acc[5][r], acc[7][r], c[r][1]);
        }
        hB = nh;

        *(f16x8*)hp = hB;
        hp += hstep;
    }
}

// ---------------------------------------------------------------------------
// K2: layer-1 fwd scan + 1-step bwd + FC epilogue. 2 tiles/wave (shared
// weights; 4 hist loads in flight per wave -> fixes R9's 690 GB/s fetch
// bottleneck). acc shared across tiles (sequential tt) to stay under the
// 256-VGPR (256,2) cap -- avoids R8's spill. grid = (NT/8, 2[model]).
// ---------------------------------------------------------------------------
__global__ __launch_bounds__(256, 2) void k2_l1(
    const float* __restrict__ dir_input,      // [32768,6]
    const float* __restrict__ lvl_Wih1, const float* __restrict__ lvl_Whh1,
    const float* __restrict__ lvl_b1,
    const float* __restrict__ vor_Wih1, const float* __restrict__ vor_Whh1,
    const float* __restrict__ vor_b1,
    const float* __restrict__ lvl_fc_W, const float* __restrict__ lvl_fc_b,
    const float* __restrict__ vor_fc_W, const float* __restrict__ vor_fc_b,
    const _Float16* __restrict__ hist, float* __restrict__ out,
    int chunk_base, int NT)
{
    const int lane  = threadIdx.x & 63;
    const int wv    = threadIdx.x >> 6;
    const int n0    = lane & 15;
    const int quad  = lane >> 4;
    const int tpair = (blockIdx.x * 4 + wv) * 2;
    const int m     = blockIdx.y;

    const float* Wih = m ? vor_Wih1 : lvl_Wih1;   // [2][128][64]
    const float* Whh = m ? vor_Whh1 : lvl_Whh1;   // [2][128][32]
    const float* bs  = m ? vor_b1   : lvl_b1;     // [2][128]

    f16x8 WA[8], WB[8], WH[8];
    f32x4 biasv[8];                               // C/D-row bias (j = 8q+4p+r)
#pragma unroll
    for (int nb = 0; nb < 8; ++nb) {
        const int g = nb >> 1, p = nb & 1;
        const int J = g * 32 + jperm(nb, n0);
        const float s = gscale(nb);
        WA[nb] = afrag8(Wih + J * 64 + quad * 8, s);
        WB[nb] = afrag8(Wih + J * 64 + 32 + quad * 8, s);
        WH[nb] = afrag8(Whh + J * 32 + quad * 8, s);
        const float4 bq = *(const float4*)(bs + g * 32 + 8 * quad + 4 * p);
        f32x4 bv; bv[0] = bq.x * s; bv[1] = bq.y * s; bv[2] = bq.z * s; bv[3] = bq.w * s;
        biasv[nb] = bv;
    }

    const _Float16* hb[2];
#pragma unroll
    for (int tt = 0; tt < 2; ++tt)
        hb[tt] = hist + ((size_t)(m * NT + tpair + tt)) * 15 * 1024 + lane * 8;

    float c1[2][4][2];
#pragma unroll
    for (int tt = 0; tt < 2; ++tt)
#pragma unroll
        for (int r = 0; r < 4; ++r) { c1[tt][r][0] = 0.0f; c1[tt][r][1] = 0.0f; }
    f16x8 h1B[2];
#pragma unroll
    for (int tt = 0; tt < 2; ++tt)
#pragma unroll
        for (int r = 0; r < 8; ++r) h1B[tt][r] = (_Float16)0.0f;
    float h1f_a[2][4], h1f_b[2][4];
    f16x8 a_f[2], a_b[2];

    // prefetch t=0 for both tiles (4 loads in flight)
    f16x8 nf[2], nb2[2];
#pragma unroll
    for (int tt = 0; tt < 2; ++tt) {
        nf[tt]  = *(const f16x8*)(hb[tt]);
        nb2[tt] = *(const f16x8*)(hb[tt] + 512);
    }

#pragma unroll 1
    for (int t = 0; t < 15; ++t) {
#pragma unroll
        for (int tt = 0; tt < 2; ++tt) { a_f[tt] = nf[tt]; a_b[tt] = nb2[tt]; }
        const int tn = (t < 14) ? (t + 1) : t;
#pragma unroll
        for (int tt = 0; tt < 2; ++tt) {
            nf[tt]  = *(const f16x8*)(hb[tt] + (size_t)tn * 1024);
            nb2[tt] = *(const f16x8*)(hb[tt] + (size_t)tn * 1024 + 512);
        }

        // sequential tiles: acc[8] reused (keeps VGPR under the (256,2) cap)
#pragma unroll
        for (int tt = 0; tt < 2; ++tt) {
            f32x4 acc[8];
#pragma unroll
            for (int nb = 0; nb < 8; ++nb)
                acc[nb] = __builtin_amdgcn_mfma_f32_16x16x32_f16(WA[nb], a_f[tt], biasv[nb], 0, 0, 0);
#pragma unroll
            for (int nb = 0; nb < 8; ++nb)
                acc[nb] = __builtin_amdgcn_mfma_f32_16x16x32_f16(WB[nb], a_b[tt], acc[nb], 0, 0, 0);
#pragma unroll
            for (int nb = 0; nb < 8; ++nb)
                acc[nb] = __builtin_amdgcn_mfma_f32_16x16x32_f16(WH[nb], h1B[tt], acc[nb], 0, 0, 0);

            f16x8 nh;
#pragma unroll
            for (int r = 0; r < 4; ++r) {
                float ha  = cellT(acc[0][r], acc[2][r], acc[4][r], acc[6][r], c1[tt][r][0]);
                float hbv = cellT(acc[1][r], acc[3][r], acc[5][r], acc[7][r], c1[tt][r][1]);
                h1f_a[tt][r] = ha; h1f_b[tt][r] = hbv;
                nh[r] = (_Float16)ha; nh[4 + r] = (_Float16)hbv;
            }
            h1B[tt] = nh;
        }
    }
    // a_f/a_b hold t=14 for both tiles (input to the 1-step L1 backward).

    // ---- L1 backward, single step from zero state (f-gate dead) ----
    float h1b_a[2][4], h1b_b[2][4];
    {
        const float* Wb = Wih + 128 * 64;   // dir 1
        const float* bb = bs + 128;
        const int nbs[6] = {0, 1, 4, 5, 6, 7};   // i, g, o slices (p=0/1 each)
        f32x4 accb[2][6];
#pragma unroll
        for (int q6 = 0; q6 < 6; ++q6) {
            const int nb = nbs[q6];
            const int g = nb >> 1, p = nb & 1;
            const int J = g * 32 + jperm(nb, n0);
            const float s = gscale(nb);
            const f16x8 wa = afrag8(Wb + J * 64 + quad * 8, s);
            const f16x8 wb = afrag8(Wb + J * 64 + 32 + quad * 8, s);
            const float4 bq = *(const float4*)(bb + g * 32 + 8 * quad + 4 * p);
            f32x4 bv; bv[0] = bq.x * s; bv[1] = bq.y * s; bv[2] = bq.z * s; bv[3] = bq.w * s;
#pragma unroll
            for (int tt = 0; tt < 2; ++tt) {
                f32x4 a = __builtin_amdgcn_mfma_f32_16x16x32_f16(wa, a_f[tt], bv, 0, 0, 0);
                a = __builtin_amdgcn_mfma_f32_16x16x32_f16(wb, a_b[tt], a, 0, 0, 0);
                accb[tt][q6] = a;
            }
        }
#pragma unroll
        for (int tt = 0; tt < 2; ++tt)
#pragma unroll
            for (int r = 0; r < 4; ++r) {
#pragma unroll
                for (int p = 0; p < 2; ++p) {
                    const float i_ = accb[tt][0 + p][r];   // -log2e * i
                    const float g_ = accb[tt][2 + p][r];   // 2log2e * g
                    const float o_ = accb[tt][4 + p][r];   // -log2e * o
                    float ei = __builtin_amdgcn_exp2f(i_);
                    float eg = __builtin_amdgcn_exp2f(g_);
                    float Bv = 1.0f + ei;
                    float C  = 1.0f + eg;
                    float cv = (eg - 1.0f) * __builtin_amdgcn_rcpf(Bv * C);
                    float eo = __builtin_amdgcn_exp2f(o_);
                    float ec = __builtin_amdgcn_exp2f(LOG2E2 * cv);
                    float h = (ec - 1.0f) * __builtin_amdgcn_rcpf((1.0f + eo) * (1.0f + ec));
                    if (p == 0) h1b_a[tt][r] = h; else h1b_b[tt][r] = h;
                }
            }
    }

    // ---- FC + masks + atomic combine. Lane holds j = 8q+r / 8q+4+r. ----
#pragma unroll
    for (int tt = 0; tt < 2; ++tt) {
        const int sbase = chunk_base + (tpair + tt) * 16;
        const int halfU = sbase >> 15;             // wave-uniform per tile

        float pr[2];
#pragma unroll
        for (int o = 0; o < 2; ++o) {
            const float* Wr = (m == 0) ? (lvl_fc_W + o * 64)
                                       : (vor_fc_W + o * 128 + halfU * 64);
            const float4 wfa = *(const float4*)(Wr + 8 * quad);
            const float4 wfb = *(const float4*)(Wr + 8 * quad + 4);
            const float4 wba = *(const float4*)(Wr + 32 + 8 * quad);
            const float4 wbb = *(const float4*)(Wr + 32 + 8 * quad + 4);
            float a = wfa.x * h1f_a[tt][0] + wfa.y * h1f_a[tt][1]
                    + wfa.z * h1f_a[tt][2] + wfa.w * h1f_a[tt][3];
            a += wfb.x * h1f_b[tt][0] + wfb.y * h1f_b[tt][1]
               + wfb.z * h1f_b[tt][2] + wfb.w * h1f_b[tt][3];
            a += wba.x * h1b_a[tt][0] + wba.y * h1b_a[tt][1]
               + wba.z * h1b_a[tt][2] + wba.w * h1b_a[tt][3];
            a += wbb.x * h1b_b[tt][0] + wbb.y * h1b_b[tt][1]
               + wbb.z * h1b_b[tt][2] + wbb.w * h1b_b[tt][3];
            pr[o] = a;
        }
#pragma unroll
        for (int o = 0; o < 2; ++o) {
            pr[o] += __shfl_xor(pr[o], 16);
            pr[o] += __shfl_xor(pr[o], 32);
        }

        if (quad == 0) {
            const int sb = sbase + n0;
            const int b  = sb & 32767;
            const float* dp = dir_input + (size_t)b * 6;
            float mx = dp[0];
            int dmax = 0;
#pragma unroll
            for (int i = 1; i < 6; ++i) {
                const float v = dp[i];
                if (v > mx) { mx = v; dmax = i; }
            }
            float mask, b0v, b1v;
            if (m == 0) {
                mask = (halfU == 0) ? ((dmax == 2 || dmax == 3) ? 1.0f : 0.0f)
                                    : ((dmax == 0 || dmax == 5) ? 1.0f : 0.0f);
                b0v = lvl_fc_b[0]; b1v = lvl_fc_b[1];
            } else {
                mask = (dmax == 1 || dmax == 4) ? 1.0f : 0.0f;
                b0v = (halfU == 0) ? vor_fc_b[0] : 0.0f;
                b1v = (halfU == 0) ? vor_fc_b[1] : 0.0f;
            }
            atomicAdd(out + (size_t)b * 2 + 0, (pr[0] + b0v) * mask);
            atomicAdd(out + (size_t)b * 2 + 1, (pr[1] + b1v) * mask);
        }
    }
}

extern "C" void kernel_launch(void* const* d_in, const int* in_sizes, int n_in,
                              void* d_out, int out_size, void* d_ws, size_t ws_size,
                              hipStream_t stream) {
    const float* dir_input = (const float*)d_in[0];
    const float* pos       = (const float*)d_in[1];
    const float* lvl_Wih0  = (const float*)d_in[2];
    const float* lvl_Whh0  = (const float*)d_in[3];
    const float* lvl_b0    = (const float*)d_in[4];
    const float* lvl_Wih1  = (const float*)d_in[5];
    const float* lvl_Whh1  = (const float*)d_in[6];
    const float* lvl_b1    = (const float*)d_in[7];
    const float* vor_Wih0  = (const float*)d_in[8];
    const float* vor_Whh0  = (const float*)d_in[9];
    const float* vor_b0    = (const float*)d_in[10];
    const float* vor_Wih1  = (const float*)d_in[11];
    const float* vor_Whh1  = (const float*)d_in[12];
    const float* vor_b1    = (const float*)d_in[13];
    const float* lvl_fc_W  = (const float*)d_in[14];
    const float* lvl_fc_b  = (const float*)d_in[15];
    const float* vor_fc_W  = (const float*)d_in[16];
    const float* vor_fc_b  = (const float*)d_in[17];
    float* out = (float*)d_out;
    _Float16* hist = (_Float16*)d_ws;

    (void)in_sizes; (void)n_in;

    hipMemsetAsync(d_out, 0, (size_t)out_size * sizeof(float), stream);

    // per sample: 2 models * 15 t * 64 k * 2 B = 3840 B of history
    int S_C = 32768;                                   // 126 MB chunk (ws-verified)
    while ((size_t)S_C * 3840ull > ws_size && S_C > 128) S_C >>= 1;

    for (int base = 0; base < 65536; base += S_C) {
        const int NT = S_C / 16;
        dim3 blk(256, 1, 1);
        dim3 g1(NT / 4, 4, 1);
        hipLaunchKernelGGL(k1_l0, g1, blk, 0, stream,
                           pos, lvl_Wih0, lvl_Whh0, lvl_b0,
                           vor_Wih0, vor_Whh0, vor_b0,
                           hist, base, NT);
        dim3 g2(NT / 8, 2, 1);
        hipLaunchKernelGGL(k2_l1, g2, blk, 0, stream,
                           dir_input, lvl_Wih1, lvl_Whh1, lvl_b1,
                           vor_Wih1, vor_Whh1, vor_b1,
                           lvl_fc_W, lvl_fc_b, vor_fc_W, vor_fc_b,
                           hist, out, base, NT);
    }
}